// Round 1
// baseline (658.086 us; speedup 1.0000x reference)
//
#include <hip/hip_runtime.h>
#include <math.h>

#define D_IN  512
#define D_HID 16
#define D_OUT 64

// ---------------------------------------------------------------------------
// K0: init deg=1.0 (self-loop) and zero acc1
__global__ void k_init(float* __restrict__ deg, float* __restrict__ acc1, int n) {
    int i = blockIdx.x * blockDim.x + threadIdx.x;
    if (i < n * D_HID) acc1[i] = 0.0f;
    if (i < n) deg[i] = 1.0f;
}

// K1: degree histogram over dst
__global__ void k_deg(const int* __restrict__ dst, float* __restrict__ deg, int E) {
    int e = blockIdx.x * blockDim.x + threadIdx.x;
    if (e < E) atomicAdd(&deg[dst[e]], 1.0f);
}

// K2: deg -> rsqrt(deg) in place
__global__ void k_rsqrt(float* __restrict__ deg, int n) {
    int i = blockIdx.x * blockDim.x + threadIdx.x;
    if (i < n) deg[i] = rsqrtf(deg[i]);
}

// K3: m1[r][j] = dis[r] * sum_k x[r][k] * W1[k][j]
// 4 threads per row, each covers 128 of the 512 k's, shfl-reduce across 4 lanes.
__global__ __launch_bounds__(256) void k_gemm1(const float* __restrict__ x,
                                               const float* __restrict__ W1,
                                               const float* __restrict__ dis,
                                               float* __restrict__ m1, int n) {
    __shared__ float w[D_IN * D_HID];  // 32 KiB
    for (int i = threadIdx.x; i < (D_IN * D_HID) / 4; i += 256)
        ((float4*)w)[i] = ((const float4*)W1)[i];
    __syncthreads();

    int gid  = blockIdx.x * blockDim.x + threadIdx.x;
    int row  = gid >> 2;
    int part = gid & 3;
    if (row >= n) return;

    const float4* xr = (const float4*)(x + (size_t)row * D_IN + part * 128);
    float acc[D_HID];
#pragma unroll
    for (int j = 0; j < D_HID; j++) acc[j] = 0.0f;

#pragma unroll 4
    for (int m = 0; m < 32; m++) {
        float4 xv = xr[m];
        int kb = part * 128 + m * 4;
        const float* w0 = &w[(kb + 0) * D_HID];
        const float* w1 = &w[(kb + 1) * D_HID];
        const float* w2 = &w[(kb + 2) * D_HID];
        const float* w3 = &w[(kb + 3) * D_HID];
#pragma unroll
        for (int j = 0; j < D_HID; j++)
            acc[j] += xv.x * w0[j] + xv.y * w1[j] + xv.z * w2[j] + xv.w * w3[j];
    }
#pragma unroll
    for (int j = 0; j < D_HID; j++) {
        acc[j] += __shfl_xor(acc[j], 1);
        acc[j] += __shfl_xor(acc[j], 2);
    }
    float s = dis[row];
    float4 o;
    o.x = s * acc[part * 4 + 0];
    o.y = s * acc[part * 4 + 1];
    o.z = s * acc[part * 4 + 2];
    o.w = s * acc[part * 4 + 3];
    ((float4*)(m1 + (size_t)row * D_HID))[part] = o;
}

// K4/K6: acc[dst][j] += msg[src][j]   (16 threads per edge)
__global__ void k_scatter(const int* __restrict__ src, const int* __restrict__ dst,
                          const float* __restrict__ msg, float* __restrict__ acc, int E) {
    int tid = blockIdx.x * blockDim.x + threadIdx.x;
    int e = tid >> 4;
    int j = tid & 15;
    if (e < E) {
        int s = src[e];
        int d = dst[e];
        atomicAdd(&acc[(size_t)d * D_HID + j], msg[(size_t)s * D_HID + j]);
    }
}

// K5: z = relu(dis[r]*(acc1 + m1) + b1[j]); acc1 <- dis[r]*z (m1b); m1 <- 0 (acc2)
__global__ void k_post1(float* __restrict__ acc1, float* __restrict__ m1,
                        const float* __restrict__ dis, const float* __restrict__ b1, int n) {
    int i = blockIdx.x * blockDim.x + threadIdx.x;
    if (i < n * D_HID) {
        int r = i >> 4, j = i & 15;
        float s = dis[r];
        float z = s * (acc1[i] + m1[i]) + b1[j];
        z = fmaxf(z, 0.0f);
        acc1[i] = s * z;
        m1[i]   = 0.0f;
    }
}

// K7: g = dis*(acc2 + m1b); out_row = g @ W2 + b2; log_softmax over 64 lanes.
// One wave (64 lanes) per node; lane = output column.
__global__ __launch_bounds__(256) void k_final(const float* __restrict__ acc2,
                                               const float* __restrict__ m1b,
                                               const float* __restrict__ dis,
                                               const float* __restrict__ W2,
                                               const float* __restrict__ b2,
                                               float* __restrict__ out, int n) {
    int lane = threadIdx.x & 63;
    int node = blockIdx.x * 4 + (threadIdx.x >> 6);
    if (node >= n) return;

    float s = dis[node];
    float g[D_HID];
    const float4* a4 = (const float4*)(acc2 + (size_t)node * D_HID);
    const float4* m4 = (const float4*)(m1b + (size_t)node * D_HID);
#pragma unroll
    for (int q = 0; q < 4; q++) {
        float4 av = a4[q], mv = m4[q];
        g[q * 4 + 0] = s * (av.x + mv.x);
        g[q * 4 + 1] = s * (av.y + mv.y);
        g[q * 4 + 2] = s * (av.z + mv.z);
        g[q * 4 + 3] = s * (av.w + mv.w);
    }
    float v = b2[lane];
#pragma unroll
    for (int j = 0; j < D_HID; j++) v += g[j] * W2[j * D_OUT + lane];

    float mx = v;
#pragma unroll
    for (int off = 32; off; off >>= 1) mx = fmaxf(mx, __shfl_xor(mx, off));
    float ev = expf(v - mx);
    float sum = ev;
#pragma unroll
    for (int off = 32; off; off >>= 1) sum += __shfl_xor(sum, off);
    out[(size_t)node * D_OUT + lane] = (v - mx) - logf(sum);
}

// ---------------------------------------------------------------------------
extern "C" void kernel_launch(void* const* d_in, const int* in_sizes, int n_in,
                              void* d_out, int out_size, void* d_ws, size_t ws_size,
                              hipStream_t stream) {
    const float* x  = (const float*)d_in[0];
    const int*   ei = (const int*)d_in[1];
    const float* W1 = (const float*)d_in[2];
    const float* b1 = (const float*)d_in[3];
    const float* W2 = (const float*)d_in[4];
    const float* b2 = (const float*)d_in[5];
    float* out = (float*)d_out;

    int n = in_sizes[0] / D_IN;   // 100000
    int E = in_sizes[1] / 2;      // 3200000
    const int* src = ei;
    const int* dst = ei + E;

    float* ws   = (float*)d_ws;
    float* deg  = ws;                         // n floats (deg -> dis)
    float* bufA = ws + n;                     // n*16 (m1, later acc2)
    float* bufB = bufA + (size_t)n * D_HID;   // n*16 (acc1, later m1b)

    const int B = 256;
    k_init  <<<(n * D_HID + B - 1) / B, B, 0, stream>>>(deg, bufB, n);
    k_deg   <<<(E + B - 1) / B, B, 0, stream>>>(dst, deg, E);
    k_rsqrt <<<(n + B - 1) / B, B, 0, stream>>>(deg, n);
    k_gemm1 <<<(n * 4 + B - 1) / B, B, 0, stream>>>(x, W1, deg, bufA, n);
    k_scatter<<<((long long)E * D_HID + B - 1) / B, B, 0, stream>>>(src, dst, bufA, bufB, E);
    k_post1 <<<(n * D_HID + B - 1) / B, B, 0, stream>>>(bufB, bufA, deg, b1, n);
    k_scatter<<<((long long)E * D_HID + B - 1) / B, B, 0, stream>>>(src, dst, bufB, bufA, E);
    k_final <<<(n + 3) / 4, B, 0, stream>>>(bufA, bufB, deg, W2, b2, out, n);
}